// Round 11
// baseline (294.975 us; speedup 1.0000x reference)
//
#include <hip/hip_runtime.h>

#define NN 50000
#define NE 800000
#define HID 256
#define HALF 128
#define CAP 48                    // bucket capacity; P(Poisson(16) >= 48) ~ 1e-9
#define MT ((NN + 63) / 64)       // 782 gemm m-tiles
#define EPT 2                     // edges per thread in mlp_fill
#define MLPB ((NE + 256 * EPT - 1) / (256 * EPT))   // 1563 blocks
#define NPREPB 782                // prep grid: 200192 threads >= 200000 uint4

typedef __attribute__((ext_vector_type(8))) short short8;   // bf16x8 frag
typedef __attribute__((ext_vector_type(8))) unsigned short ush8;
typedef __attribute__((ext_vector_type(4))) float floatx4;  // fp32 acc frag

#define WSCALE 1.52587890625e-5f  // 2^-16 fixed-point weight scale

// fp32 -> bf16 round-nearest-even (finite inputs)
__device__ inline unsigned short f2b(float f) {
    unsigned int u = __float_as_uint(f);
    return (unsigned short)((u + 0x7FFFu + ((u >> 16) & 1u)) >> 16);
}
// bf16 bits -> fp32 (exact)
__device__ inline float b2f(unsigned int u) { return __uint_as_float(u << 16); }

__device__ inline float fsigmoid(float x) {
    return __builtin_amdgcn_rcpf(1.0f + __expf(-x));
}

// ---- prep: zero cntp (3.2 MB, one counter per 64B line) + Wt transpose -----
__global__ __launch_bounds__(256) void k_prep(const float* __restrict__ Wc,
                                              unsigned short* __restrict__ Wt,
                                              uint4* __restrict__ zb) {
    int t = blockIdx.x * 256 + threadIdx.x;     // 200192 threads
    if (t < 200000) zb[t] = make_uint4(0u, 0u, 0u, 0u);
    if (t < 65536) {
        int n = t >> 8, k = t & 255;
        Wt[n * 256 + k] = f2b(Wc[k * 256 + n]);
    }
}

// ---- edge MLP + bucket fill, EPT=2 (FROZEN, R9/R10-verified) ---------------
__global__ __launch_bounds__(256, 6) void k_mlp_fill(
    const float* __restrict__ ea, const int* __restrict__ eidx,
    const float* __restrict__ W1, const float* __restrict__ b1,
    const float* __restrict__ W2, const float* __restrict__ b2,
    unsigned int* __restrict__ cntp, unsigned int* __restrict__ epk) {
    __shared__ float4 wp[HALF];   // {W1[0][j], W1[1][j], W1[2][j], b1[j]}
    __shared__ __align__(16) float w2s[HALF];
    int tid = threadIdx.x;
    int e0 = blockIdx.x * (256 * EPT) + tid;
    int row[EPT], col[EPT];
    float a0[EPT], a1[EPT], a2[EPT];
    bool ok[EPT];
#pragma unroll
    for (int i = 0; i < EPT; ++i) {             // plain loads: drained once at bar
        int ei = e0 + i * 256;                  // i-slices stay lane-coalesced
        ok[i] = ei < NE;
        int ec = ok[i] ? ei : (NE - 1);         // clamp for loads only
        row[i] = eidx[ec];
        col[i] = eidx[NE + ec];
        a0[i] = ea[3 * ec];
        a1[i] = ea[3 * ec + 1];
        a2[i] = ea[3 * ec + 2];
    }
    if (tid < HALF) {
        wp[tid] = make_float4(W1[tid], W1[HALF + tid], W1[2 * HALF + tid], b1[tid]);
        w2s[tid] = W2[tid];
    }
    __syncthreads();
    // atomics AFTER the barrier: in flight across the entire compute loop
    unsigned slot[EPT];
#pragma unroll
    for (int i = 0; i < EPT; ++i)
        slot[i] = ok[i] ? atomicAdd(&cntp[col[i] * 16], 1u) : 0xFFFFFFFFu;
    float acc[EPT] = {0.f, 0.f};
#pragma unroll 1
    for (int g = 0; g < HALF / 4; ++g) {        // rolled: keeps VGPR bounded
        int j = g * 4;
        float4 w0 = wp[j], w1 = wp[j + 1], w2v = wp[j + 2], w3 = wp[j + 3];
        float4 v2 = *(const float4*)&w2s[j];
#pragma unroll
        for (int i = 0; i < EPT; ++i) {         // indep chains = ILP
            float t0 = fmaf(a0[i], w0.x, fmaf(a1[i], w0.y, fmaf(a2[i], w0.z, w0.w)));
            float t1 = fmaf(a0[i], w1.x, fmaf(a1[i], w1.y, fmaf(a2[i], w1.z, w1.w)));
            float t2 = fmaf(a0[i], w2v.x, fmaf(a1[i], w2v.y, fmaf(a2[i], w2v.z, w2v.w)));
            float t3 = fmaf(a0[i], w3.x, fmaf(a1[i], w3.y, fmaf(a2[i], w3.z, w3.w)));
            float s0 = t0 * fsigmoid(t0);       // silu
            float s1 = t1 * fsigmoid(t1);
            float s2 = t2 * fsigmoid(t2);
            float s3 = t3 * fsigmoid(t3);
            acc[i] = fmaf(s0, v2.x, fmaf(s1, v2.y, fmaf(s2, v2.z, fmaf(s3, v2.w, acc[i]))));
        }
    }
    float bb = b2[0];
#pragma unroll
    for (int i = 0; i < EPT; ++i) {
        float wv = fsigmoid(acc[i] + bb);
        unsigned q = __float2uint_rn(wv * 65536.0f);   // 16-bit fixed point
        if (q > 65535u) q = 65535u;
        if (ok[i] && slot[i] < CAP)             // first wait on `slot` is here
            epk[col[i] * CAP + slot[i]] = (unsigned)row[i] | (q << 16);
    }
}

// ---- GEMM + inline deg (FROZEN, R9/R10-verified) ---------------------------
__global__ __launch_bounds__(256) void k_gemm_deg(
    const float* __restrict__ A, const unsigned short* __restrict__ Wt,
    const unsigned int* __restrict__ cntp, const uint4* __restrict__ epk4,
    unsigned short* __restrict__ xs) {
    __shared__ __align__(16) unsigned short As[8 * 64 * 40];   // [chunk][64][40]
    __shared__ float dinvs[64];
    int tid = threadIdx.x;
    int wave = tid >> 6, lane = tid & 63;
    int mbase = blockIdx.x * 64, nbase = wave * 64;
    int lrow = lane & 15, lg = lane >> 4;
    int srow = tid >> 2, skg = tid & 3;
    int arow = mbase + srow;
    if (arow >= NN) arow = NN - 1;   // clamp: pollutes only unwritten rows
    const float* Ap = A + (size_t)arow * HID + skg * 8;

    // --- inline deg for rows [mbase, mbase+64): L2/L3-hot epk reads ---------
    if (tid < 64) {
        int drow = mbase + tid;
        if (drow >= NN) drow = NN - 1;
        int dcn = (int)cntp[drow * 16];
        if (dcn > CAP) dcn = CAP;
        const uint4* dbp = epk4 + (size_t)drow * (CAP / 4);
        unsigned s = 0;                          // exact: <= 48 * 65535 < 2^22
#pragma unroll
        for (int i = 0; i < CAP / 4; ++i) {
            uint4 qv = dbp[i];
            int k0 = i * 4;
            s += (k0 + 0 < dcn) ? (qv.x >> 16) : 0u;
            s += (k0 + 1 < dcn) ? (qv.y >> 16) : 0u;
            s += (k0 + 2 < dcn) ? (qv.z >> 16) : 0u;
            s += (k0 + 3 < dcn) ? (qv.w >> 16) : 0u;
        }
        dinvs[tid] = rsqrtf(fmaf((float)s, WSCALE, 1.0f));
    }

#define PACKST(c, f0, f1) { uint4 pk;                                   \
    pk.x = (unsigned)f2b(f0.x) | ((unsigned)f2b(f0.y) << 16);           \
    pk.y = (unsigned)f2b(f0.z) | ((unsigned)f2b(f0.w) << 16);           \
    pk.z = (unsigned)f2b(f1.x) | ((unsigned)f2b(f1.y) << 16);           \
    pk.w = (unsigned)f2b(f1.z) | ((unsigned)f2b(f1.w) << 16);           \
    *(uint4*)&As[(c) * 2560 + srow * 40 + skg * 8] = pk; }

    // stage full K=256 (8 chunks of 32), 4 row-pairs of loads in flight
#pragma unroll
    for (int g = 0; g < 2; ++g) {
        int c0 = g * 4;
        float4 fa0 = *(const float4*)(Ap + (c0 + 0) * 32);
        float4 fb0 = *(const float4*)(Ap + (c0 + 0) * 32 + 4);
        float4 fa1 = *(const float4*)(Ap + (c0 + 1) * 32);
        float4 fb1 = *(const float4*)(Ap + (c0 + 1) * 32 + 4);
        float4 fa2 = *(const float4*)(Ap + (c0 + 2) * 32);
        float4 fb2 = *(const float4*)(Ap + (c0 + 2) * 32 + 4);
        float4 fa3 = *(const float4*)(Ap + (c0 + 3) * 32);
        float4 fb3 = *(const float4*)(Ap + (c0 + 3) * 32 + 4);
        PACKST(c0 + 0, fa0, fb0);
        PACKST(c0 + 1, fa1, fb1);
        PACKST(c0 + 2, fa2, fb2);
        PACKST(c0 + 3, fa3, fb3);
    }
    __syncthreads();   // the ONLY barrier (orders As AND dinvs)

    floatx4 acc[4][4];
#pragma unroll
    for (int t = 0; t < 4; ++t)
#pragma unroll
        for (int u = 0; u < 4; ++u)
            acc[t][u] = (floatx4){0.f, 0.f, 0.f, 0.f};

#pragma unroll
    for (int c = 0; c < 8; ++c) {
        short8 af[4], bf[4];
#pragma unroll
        for (int t = 0; t < 4; ++t)
            af[t] = *(const short8*)&As[c * 2560 + (t * 16 + lrow) * 40 + lg * 8];
#pragma unroll
        for (int u = 0; u < 4; ++u)
            bf[u] = *(const short8*)&Wt[(nbase + u * 16 + lrow) * 256 + c * 32 + lg * 8];
#pragma unroll
        for (int t = 0; t < 4; ++t)
#pragma unroll
            for (int u = 0; u < 4; ++u)
                acc[t][u] = __builtin_amdgcn_mfma_f32_16x16x32_bf16(
                    af[t], bf[u], acc[t][u], 0, 0, 0);
    }
    // C/D layout (m89-verified): col = lane&15, row = (lane>>4)*4 + reg
#pragma unroll
    for (int t = 0; t < 4; ++t) {
        int rowb = mbase + t * 16 + lg * 4;
#pragma unroll
        for (int r = 0; r < 4; ++r) {
            int row = rowb + r;
            if (row < NN) {
                float di = dinvs[t * 16 + lg * 4 + r];
#pragma unroll
                for (int u = 0; u < 4; ++u)
                    xs[row * 256 + nbase + u * 16 + lrow] = f2b(acc[t][u][r] * di);
            }
        }
    }
}

// ---- aggregate v3: 2 records per gather instruction.
//      Lanes 0..31 service record 2i, lanes 32..63 record 2i+1; each lane
//      loads ushort8 (16B, 8 cols). Halves VMEM gather instructions vs R10
//      (bytes & line-requests unchanged). Final __shfl_xor(32) merges halves.
//      deg-sum arithmetic bit-identical to R10 (exact integer, order-free). --
#define CH16B(W0, W1, W2, W3, BASE)                                         \
    {                                                                       \
        unsigned pp[16];                                                    \
        pp[0] = W0.x; pp[1] = W0.y; pp[2] = W0.z; pp[3] = W0.w;             \
        pp[4] = W1.x; pp[5] = W1.y; pp[6] = W1.z; pp[7] = W1.w;             \
        pp[8] = W2.x; pp[9] = W2.y; pp[10] = W2.z; pp[11] = W2.w;           \
        pp[12] = W3.x; pp[13] = W3.y; pp[14] = W3.z; pp[15] = W3.w;         \
        _Pragma("unroll")                                                   \
        for (int k = 0; k < 16; ++k)                                        \
            if ((BASE) + k >= cn) pp[k] = 0u;                               \
        _Pragma("unroll")                                                   \
        for (int k = 0; k < 16; ++k) s += pp[k] >> 16;                      \
        ush8 vv[8]; float nn[8];                                            \
        _Pragma("unroll")                                                   \
        for (int i = 0; i < 8; ++i) {                                       \
            unsigned sel = hi ? pp[2 * i + 1] : pp[2 * i];                  \
            vv[i] = *(const ush8*)&xs[(sel & 0xFFFFu) * 256 + c8];          \
            nn[i] = (float)(sel >> 16) * WSCALE;                            \
        }                                                                   \
        _Pragma("unroll")                                                   \
        for (int i = 0; i < 8; ++i)                                         \
            _Pragma("unroll")                                               \
            for (int j = 0; j < 8; ++j)                                     \
                acc[j] = fmaf(b2f((unsigned short)vv[i][j]), nn[i], acc[j]);\
    }

__global__ __launch_bounds__(256, 4) void k_aggregate(
    const unsigned short* __restrict__ xs, const unsigned int* __restrict__ cntp,
    const unsigned int* __restrict__ epk, const float* __restrict__ bc,
    float* __restrict__ out) {
    int n = blockIdx.x * 4 + (threadIdx.x >> 6);
    int lane = threadIdx.x & 63;
    if (n >= NN) return;
    int hi = lane >> 5;                        // 0: even records, 1: odd records
    int c8 = (lane & 31) * 8;                  // 8 cols per lane
    int cn = (int)cntp[n * 16];
    if (cn > CAP) cn = CAP;                    // drop-guard clamp
    const uint4* bp = (const uint4*)(epk + (size_t)n * CAP);  // 12 uint4
    uint4 A0 = bp[0], A1 = bp[1], A2 = bp[2], A3 = bp[3];     // records 0..15
    ush8 xv = *(const ush8*)&xs[n * 256 + c8];
    float acc[8];
#pragma unroll
    for (int j = 0; j < 8; ++j)                // self term: lo half only
        acc[j] = hi ? 0.f : b2f((unsigned short)xv[j]);
    unsigned s = 0;                            // deg-sum, exact u32

    CH16B(A0, A1, A2, A3, 0);
    if (cn > 16) {                             // wave-uniform branch
        uint4 B0 = bp[4], B1 = bp[5], B2 = bp[6], B3 = bp[7];
        CH16B(B0, B1, B2, B3, 16);
        if (cn > 32) {
            uint4 C0 = bp[8], C1 = bp[9], C2 = bp[10], C3 = bp[11];
            CH16B(C0, C1, C2, C3, 32);
        }
    }
#pragma unroll
    for (int j = 0; j < 8; ++j)                // merge even/odd halves
        acc[j] += __shfl_xor(acc[j], 32);
    float di = rsqrtf(fmaf((float)s, WSCALE, 1.0f));   // == gemm's dinv, exact
    if (hi == 0) {                             // lanes 0..31 store 32B each
        float4 bv0 = *(const float4*)&bc[c8];
        float4 bv1 = *(const float4*)&bc[c8 + 4];
        float4 r0, r1;
        r0.x = fmaf(acc[0], di, bv0.x);
        r0.y = fmaf(acc[1], di, bv0.y);
        r0.z = fmaf(acc[2], di, bv0.z);
        r0.w = fmaf(acc[3], di, bv0.w);
        r1.x = fmaf(acc[4], di, bv1.x);
        r1.y = fmaf(acc[5], di, bv1.y);
        r1.z = fmaf(acc[6], di, bv1.z);
        r1.w = fmaf(acc[7], di, bv1.w);
        *(float4*)&out[n * 256 + c8] = r0;
        *(float4*)&out[n * 256 + c8 + 4] = r1;
    }
}

extern "C" void kernel_launch(void* const* d_in, const int* in_sizes, int n_in,
                              void* d_out, int out_size, void* d_ws, size_t ws_size,
                              hipStream_t stream) {
    const float* h   = (const float*)d_in[0];
    const int* eidx  = (const int*)d_in[1];   // [2, NE]: [0]=src(row), [1]=dst(col)
    const float* ea  = (const float*)d_in[2];
    const float* W1  = (const float*)d_in[3];
    const float* b1  = (const float*)d_in[4];
    const float* W2  = (const float*)d_in[5];
    const float* b2  = (const float*)d_in[6];
    const float* Wc  = (const float*)d_in[7];
    const float* bc  = (const float*)d_in[8];
    float* out = (float*)d_out;

    // workspace layout (~38.5 MB), all 16B-aligned
    char* p = (char*)d_ws;
    unsigned int* cntp = (unsigned int*)p;   p += (size_t)NN * 16 * 4;     // 3.2 MB
    unsigned int* epk  = (unsigned int*)p;   p += (size_t)NN * CAP * 4;    // 9.6 MB
    unsigned short* xs = (unsigned short*)p; p += (size_t)NN * HID * 2;    // 25.6 MB
    unsigned short* Wt = (unsigned short*)p;                               // 0.13 MB

    k_prep<<<NPREPB, 256, 0, stream>>>(Wc, Wt, (uint4*)cntp);
    k_mlp_fill<<<MLPB, 256, 0, stream>>>(ea, eidx, W1, b1, W2, b2, cntp, epk);
    k_gemm_deg<<<MT, 256, 0, stream>>>(h, Wt, cntp, (const uint4*)epk, xs);
    k_aggregate<<<(NN + 3) / 4, 256, 0, stream>>>(xs, cntp, epk, bc, out);
}

// Round 13
// 253.342 us; speedup vs baseline: 1.1643x; 1.1643x over previous
//
#include <hip/hip_runtime.h>

#define NN 50000
#define NE 800000
#define HID 256
#define HALF 128
#define CAP 48                    // bucket capacity; P(Poisson(16) >= 48) ~ 1e-9
#define MT ((NN + 63) / 64)       // 782 gemm m-tiles
#define EPT 2                     // edges per thread in mlp_fill
#define MLPB ((NE + 256 * EPT - 1) / (256 * EPT))   // 1563 blocks
#define NPREPB 782                // prep grid: 200192 threads >= 200000 uint4

typedef __attribute__((ext_vector_type(8))) short short8;   // bf16x8 frag
typedef __attribute__((ext_vector_type(4))) float floatx4;  // fp32 acc frag

#define WSCALE 1.52587890625e-5f  // 2^-16 fixed-point weight scale

// fp32 -> bf16 round-nearest-even (finite inputs)
__device__ inline unsigned short f2b(float f) {
    unsigned int u = __float_as_uint(f);
    return (unsigned short)((u + 0x7FFFu + ((u >> 16) & 1u)) >> 16);
}
// bf16 bits -> fp32 (exact)
__device__ inline float b2f(unsigned int u) { return __uint_as_float(u << 16); }

__device__ inline float fsigmoid(float x) {
    return __builtin_amdgcn_rcpf(1.0f + __expf(-x));
}

// ---- prep: zero cntp (3.2 MB, one counter per 64B line) + Wt transpose -----
__global__ __launch_bounds__(256) void k_prep(const float* __restrict__ Wc,
                                              unsigned short* __restrict__ Wt,
                                              uint4* __restrict__ zb) {
    int t = blockIdx.x * 256 + threadIdx.x;     // 200192 threads
    if (t < 200000) zb[t] = make_uint4(0u, 0u, 0u, 0u);
    if (t < 65536) {
        int n = t >> 8, k = t & 255;
        Wt[n * 256 + k] = f2b(Wc[k * 256 + n]);
    }
}

// ---- edge MLP + bucket fill, EPT=2 (FROZEN, R9/R10-verified) ---------------
__global__ __launch_bounds__(256, 6) void k_mlp_fill(
    const float* __restrict__ ea, const int* __restrict__ eidx,
    const float* __restrict__ W1, const float* __restrict__ b1,
    const float* __restrict__ W2, const float* __restrict__ b2,
    unsigned int* __restrict__ cntp, unsigned int* __restrict__ epk) {
    __shared__ float4 wp[HALF];   // {W1[0][j], W1[1][j], W1[2][j], b1[j]}
    __shared__ __align__(16) float w2s[HALF];
    int tid = threadIdx.x;
    int e0 = blockIdx.x * (256 * EPT) + tid;
    int row[EPT], col[EPT];
    float a0[EPT], a1[EPT], a2[EPT];
    bool ok[EPT];
#pragma unroll
    for (int i = 0; i < EPT; ++i) {             // plain loads: drained once at bar
        int ei = e0 + i * 256;                  // i-slices stay lane-coalesced
        ok[i] = ei < NE;
        int ec = ok[i] ? ei : (NE - 1);         // clamp for loads only
        row[i] = eidx[ec];
        col[i] = eidx[NE + ec];
        a0[i] = ea[3 * ec];
        a1[i] = ea[3 * ec + 1];
        a2[i] = ea[3 * ec + 2];
    }
    if (tid < HALF) {
        wp[tid] = make_float4(W1[tid], W1[HALF + tid], W1[2 * HALF + tid], b1[tid]);
        w2s[tid] = W2[tid];
    }
    __syncthreads();
    // atomics AFTER the barrier: in flight across the entire compute loop
    unsigned slot[EPT];
#pragma unroll
    for (int i = 0; i < EPT; ++i)
        slot[i] = ok[i] ? atomicAdd(&cntp[col[i] * 16], 1u) : 0xFFFFFFFFu;
    float acc[EPT] = {0.f, 0.f};
#pragma unroll 1
    for (int g = 0; g < HALF / 4; ++g) {        // rolled: keeps VGPR bounded
        int j = g * 4;
        float4 w0 = wp[j], w1 = wp[j + 1], w2v = wp[j + 2], w3 = wp[j + 3];
        float4 v2 = *(const float4*)&w2s[j];
#pragma unroll
        for (int i = 0; i < EPT; ++i) {         // indep chains = ILP
            float t0 = fmaf(a0[i], w0.x, fmaf(a1[i], w0.y, fmaf(a2[i], w0.z, w0.w)));
            float t1 = fmaf(a0[i], w1.x, fmaf(a1[i], w1.y, fmaf(a2[i], w1.z, w1.w)));
            float t2 = fmaf(a0[i], w2v.x, fmaf(a1[i], w2v.y, fmaf(a2[i], w2v.z, w2v.w)));
            float t3 = fmaf(a0[i], w3.x, fmaf(a1[i], w3.y, fmaf(a2[i], w3.z, w3.w)));
            float s0 = t0 * fsigmoid(t0);       // silu
            float s1 = t1 * fsigmoid(t1);
            float s2 = t2 * fsigmoid(t2);
            float s3 = t3 * fsigmoid(t3);
            acc[i] = fmaf(s0, v2.x, fmaf(s1, v2.y, fmaf(s2, v2.z, fmaf(s3, v2.w, acc[i]))));
        }
    }
    float bb = b2[0];
#pragma unroll
    for (int i = 0; i < EPT; ++i) {
        float wv = fsigmoid(acc[i] + bb);
        unsigned q = __float2uint_rn(wv * 65536.0f);   // 16-bit fixed point
        if (q > 65535u) q = 65535u;
        if (ok[i] && slot[i] < CAP)             // first wait on `slot` is here
            epk[col[i] * CAP + slot[i]] = (unsigned)row[i] | (q << 16);
    }
}

// ---- GEMM + inline deg (FROZEN, R9/R10-verified) ---------------------------
__global__ __launch_bounds__(256) void k_gemm_deg(
    const float* __restrict__ A, const unsigned short* __restrict__ Wt,
    const unsigned int* __restrict__ cntp, const uint4* __restrict__ epk4,
    unsigned short* __restrict__ xs) {
    __shared__ __align__(16) unsigned short As[8 * 64 * 40];   // [chunk][64][40]
    __shared__ float dinvs[64];
    int tid = threadIdx.x;
    int wave = tid >> 6, lane = tid & 63;
    int mbase = blockIdx.x * 64, nbase = wave * 64;
    int lrow = lane & 15, lg = lane >> 4;
    int srow = tid >> 2, skg = tid & 3;
    int arow = mbase + srow;
    if (arow >= NN) arow = NN - 1;   // clamp: pollutes only unwritten rows
    const float* Ap = A + (size_t)arow * HID + skg * 8;

    // --- inline deg for rows [mbase, mbase+64): L2/L3-hot epk reads ---------
    if (tid < 64) {
        int drow = mbase + tid;
        if (drow >= NN) drow = NN - 1;
        int dcn = (int)cntp[drow * 16];
        if (dcn > CAP) dcn = CAP;
        const uint4* dbp = epk4 + (size_t)drow * (CAP / 4);
        unsigned s = 0;                          // exact: <= 48 * 65535 < 2^22
#pragma unroll
        for (int i = 0; i < CAP / 4; ++i) {
            uint4 qv = dbp[i];
            int k0 = i * 4;
            s += (k0 + 0 < dcn) ? (qv.x >> 16) : 0u;
            s += (k0 + 1 < dcn) ? (qv.y >> 16) : 0u;
            s += (k0 + 2 < dcn) ? (qv.z >> 16) : 0u;
            s += (k0 + 3 < dcn) ? (qv.w >> 16) : 0u;
        }
        dinvs[tid] = rsqrtf(fmaf((float)s, WSCALE, 1.0f));
    }

#define PACKST(c, f0, f1) { uint4 pk;                                   \
    pk.x = (unsigned)f2b(f0.x) | ((unsigned)f2b(f0.y) << 16);           \
    pk.y = (unsigned)f2b(f0.z) | ((unsigned)f2b(f0.w) << 16);           \
    pk.z = (unsigned)f2b(f1.x) | ((unsigned)f2b(f1.y) << 16);           \
    pk.w = (unsigned)f2b(f1.z) | ((unsigned)f2b(f1.w) << 16);           \
    *(uint4*)&As[(c) * 2560 + srow * 40 + skg * 8] = pk; }

    // stage full K=256 (8 chunks of 32), 4 row-pairs of loads in flight
#pragma unroll
    for (int g = 0; g < 2; ++g) {
        int c0 = g * 4;
        float4 fa0 = *(const float4*)(Ap + (c0 + 0) * 32);
        float4 fb0 = *(const float4*)(Ap + (c0 + 0) * 32 + 4);
        float4 fa1 = *(const float4*)(Ap + (c0 + 1) * 32);
        float4 fb1 = *(const float4*)(Ap + (c0 + 1) * 32 + 4);
        float4 fa2 = *(const float4*)(Ap + (c0 + 2) * 32);
        float4 fb2 = *(const float4*)(Ap + (c0 + 2) * 32 + 4);
        float4 fa3 = *(const float4*)(Ap + (c0 + 3) * 32);
        float4 fb3 = *(const float4*)(Ap + (c0 + 3) * 32 + 4);
        PACKST(c0 + 0, fa0, fb0);
        PACKST(c0 + 1, fa1, fb1);
        PACKST(c0 + 2, fa2, fb2);
        PACKST(c0 + 3, fa3, fb3);
    }
    __syncthreads();   // the ONLY barrier (orders As AND dinvs)

    floatx4 acc[4][4];
#pragma unroll
    for (int t = 0; t < 4; ++t)
#pragma unroll
        for (int u = 0; u < 4; ++u)
            acc[t][u] = (floatx4){0.f, 0.f, 0.f, 0.f};

#pragma unroll
    for (int c = 0; c < 8; ++c) {
        short8 af[4], bf[4];
#pragma unroll
        for (int t = 0; t < 4; ++t)
            af[t] = *(const short8*)&As[c * 2560 + (t * 16 + lrow) * 40 + lg * 8];
#pragma unroll
        for (int u = 0; u < 4; ++u)
            bf[u] = *(const short8*)&Wt[(nbase + u * 16 + lrow) * 256 + c * 32 + lg * 8];
#pragma unroll
        for (int t = 0; t < 4; ++t)
#pragma unroll
            for (int u = 0; u < 4; ++u)
                acc[t][u] = __builtin_amdgcn_mfma_f32_16x16x32_bf16(
                    af[t], bf[u], acc[t][u], 0, 0, 0);
    }
    // C/D layout (m89-verified): col = lane&15, row = (lane>>4)*4 + reg
#pragma unroll
    for (int t = 0; t < 4; ++t) {
        int rowb = mbase + t * 16 + lg * 4;
#pragma unroll
        for (int r = 0; r < 4; ++r) {
            int row = rowb + r;
            if (row < NN) {
                float di = dinvs[t * 16 + lg * 4 + r];
#pragma unroll
                for (int u = 0; u < 4; ++u)
                    xs[row * 256 + nbase + u * 16 + lrow] = f2b(acc[t][u][r] * di);
            }
        }
    }
}

// ---- aggregate: out[n] = dinv[n]*(xs[n] + sum_e w_e*xs[row_e]) + bc.
//      16-record chunks: all record words loaded upfront, 16 gathers in
//      flight before consumption; wave-uniform skip for cn>16/32.
//      deg-sum computed inline from the same predicated records ->
//      bit-identical dinv to k_gemm_deg's. ----------------------------------
#define CH16(W0, W1, W2, W3, BASE)                                          \
    {                                                                       \
        unsigned pp[16];                                                    \
        pp[0] = W0.x; pp[1] = W0.y; pp[2] = W0.z; pp[3] = W0.w;             \
        pp[4] = W1.x; pp[5] = W1.y; pp[6] = W1.z; pp[7] = W1.w;             \
        pp[8] = W2.x; pp[9] = W2.y; pp[10] = W2.z; pp[11] = W2.w;           \
        pp[12] = W3.x; pp[13] = W3.y; pp[14] = W3.z; pp[15] = W3.w;         \
        _Pragma("unroll")                                                   \
        for (int k = 0; k < 16; ++k)                                        \
            if ((BASE) + k >= cn) pp[k] = 0u;                               \
        ushort4 vv[16];                                                     \
        _Pragma("unroll")                                                   \
        for (int k = 0; k < 16; ++k)                                        \
            vv[k] = *(const ushort4*)&xs[(pp[k] & 0xFFFFu) * 256 + c4];     \
        _Pragma("unroll")                                                   \
        for (int k = 0; k < 16; ++k) {                                      \
            unsigned qw = pp[k] >> 16;                                      \
            s += qw;                                                        \
            float nk = (float)qw * WSCALE;                                  \
            ax = fmaf(b2f(vv[k].x), nk, ax); ay = fmaf(b2f(vv[k].y), nk, ay); \
            az = fmaf(b2f(vv[k].z), nk, az); aw = fmaf(b2f(vv[k].w), nk, aw); \
        }                                                                   \
    }

__global__ __launch_bounds__(256, 4) void k_aggregate(
    const unsigned short* __restrict__ xs, const unsigned int* __restrict__ cntp,
    const unsigned int* __restrict__ epk, const float* __restrict__ bc,
    float* __restrict__ out) {
    int n = blockIdx.x * 4 + (threadIdx.x >> 6);
    int lane = threadIdx.x & 63;
    if (n >= NN) return;
    int c4 = lane * 4;
    int cn = (int)cntp[n * 16];
    if (cn > CAP) cn = CAP;                    // drop-guard clamp
    const uint4* bp = (const uint4*)(epk + (size_t)n * CAP);  // 12 uint4
    uint4 A0 = bp[0], A1 = bp[1], A2 = bp[2], A3 = bp[3];     // records 0..15
    ushort4 xv = *(const ushort4*)&xs[n * 256 + c4];
    float ax = b2f(xv.x), ay = b2f(xv.y), az = b2f(xv.z), aw = b2f(xv.w);
    unsigned s = 0;                            // deg-sum, exact u32

    CH16(A0, A1, A2, A3, 0);
    if (cn > 16) {                             // wave-uniform branch
        uint4 B0 = bp[4], B1 = bp[5], B2 = bp[6], B3 = bp[7];
        CH16(B0, B1, B2, B3, 16);
        if (cn > 32) {
            uint4 C0 = bp[8], C1 = bp[9], C2 = bp[10], C3 = bp[11];
            CH16(C0, C1, C2, C3, 32);
        }
    }
    float di = rsqrtf(fmaf((float)s, WSCALE, 1.0f));   // == gemm's dinv, exact
    float4 bv = *(const float4*)&bc[c4];
    float4 res;
    res.x = fmaf(ax, di, bv.x);
    res.y = fmaf(ay, di, bv.y);
    res.z = fmaf(az, di, bv.z);
    res.w = fmaf(aw, di, bv.w);
    *(float4*)&out[n * 256 + c4] = res;
}

extern "C" void kernel_launch(void* const* d_in, const int* in_sizes, int n_in,
                              void* d_out, int out_size, void* d_ws, size_t ws_size,
                              hipStream_t stream) {
    const float* h   = (const float*)d_in[0];
    const int* eidx  = (const int*)d_in[1];   // [2, NE]: [0]=src(row), [1]=dst(col)
    const float* ea  = (const float*)d_in[2];
    const float* W1  = (const float*)d_in[3];
    const float* b1  = (const float*)d_in[4];
    const float* W2  = (const float*)d_in[5];
    const float* b2  = (const float*)d_in[6];
    const float* Wc  = (const float*)d_in[7];
    const float* bc  = (const float*)d_in[8];
    float* out = (float*)d_out;

    // workspace layout (~38.5 MB), all 16B-aligned
    char* p = (char*)d_ws;
    unsigned int* cntp = (unsigned int*)p;   p += (size_t)NN * 16 * 4;     // 3.2 MB
    unsigned int* epk  = (unsigned int*)p;   p += (size_t)NN * CAP * 4;    // 9.6 MB
    unsigned short* xs = (unsigned short*)p; p += (size_t)NN * HID * 2;    // 25.6 MB
    unsigned short* Wt = (unsigned short*)p;                               // 0.13 MB

    k_prep<<<NPREPB, 256, 0, stream>>>(Wc, Wt, (uint4*)cntp);
    k_mlp_fill<<<MLPB, 256, 0, stream>>>(ea, eidx, W1, b1, W2, b2, cntp, epk);
    k_gemm_deg<<<MT, 256, 0, stream>>>(h, Wt, cntp, (const uint4*)epk, xs);
    k_aggregate<<<(NN + 3) / 4, 256, 0, stream>>>(xs, cntp, epk, bc, out);
}